// Round 17
// baseline (521.843 us; speedup 1.0000x reference)
//
#include <hip/hip_runtime.h>
#include <stdint.h>

typedef __attribute__((ext_vector_type(4))) float f32x4;
typedef __attribute__((ext_vector_type(8))) __bf16 bf16x8;
typedef __attribute__((ext_vector_type(4))) unsigned int u32x4;
typedef __attribute__((ext_vector_type(4))) unsigned short u16x4;

#define TOK 49
#define NHEAD 16
#define HDIM 32
#define CDIM 512
#define NB 2048
#define MTOT (NB * TOK) /* 100352 */
#define ATT_SCALE 0.17677669529663687f
#define LOG2E 1.4426950408889634f

__device__ __forceinline__ unsigned short f2bf(float f) {
  return __builtin_bit_cast(unsigned short, (__bf16)f);
}
__device__ __forceinline__ float bf2f(unsigned short u) {
  return __builtin_bit_cast(float, (uint32_t)u << 16);
}

__device__ __forceinline__ void gl_lds16(const void* g, const void* lds) {
  __builtin_amdgcn_global_load_lds(
      (__attribute__((address_space(1))) void*)(uintptr_t)g,
      (__attribute__((address_space(3))) void*)(uint32_t)(uintptr_t)lds,
      16, 0, 0);
}

__device__ __forceinline__ f32x4 mfma16(bf16x8 a, bf16x8 b, f32x4 c) {
  return __builtin_amdgcn_mfma_f32_16x16x32_bf16(a, b, c, 0, 0, 0);
}

// ---- K0: merged prep (one launch replaces three) ----
// job A (blocks [0,3072)):    weff = Wqkv + Bup@Adown -> bf16; Q-rows (o<512)
//                             prescaled by ATT_SCALE*LOG2E (folds attn scale
//                             + exp->exp2 conversion into the GEMM).
// job B (blocks [3072,3078)): bq2 = bqkv with Q-rows prescaled (f32).
// job C (blocks [3078,3334)): wpb = bf16(Wproj), 65536 f32x4 groups.
// job D (blocks [3334,...)):  xb = bf16(x), grid-stride.
__global__ __launch_bounds__(256) void k_prep_all(
    const float* __restrict__ Wqkv, const float* __restrict__ Bup,
    const float* __restrict__ Adown, const float* __restrict__ bqkv,
    const float* __restrict__ Wproj, const float* __restrict__ x,
    unsigned short* __restrict__ weff, float* __restrict__ bq2,
    unsigned short* __restrict__ wpb, unsigned short* __restrict__ xb) {
  const int bid = blockIdx.x;
  const int t = threadIdx.x;
  if (bid < 3072) {
    const int idx = bid * 256 + t;  // < 786432 exactly
    const int o = idx >> 9, i = idx & 511;
    float v = Wqkv[idx];
#pragma unroll
    for (int r = 0; r < 4; r++) v += Bup[o * 4 + r] * Adown[r * 512 + i];
    if (o < 512) v *= (ATT_SCALE * LOG2E);
    weff[idx] = f2bf(v);
  } else if (bid < 3078) {
    const int o = (bid - 3072) * 256 + t;
    if (o < 3 * CDIM) {
      float v = bqkv[o];
      if (o < 512) v *= (ATT_SCALE * LOG2E);
      bq2[o] = v;
    }
  } else if (bid < 3334) {
    const int i = (bid - 3078) * 256 + t;  // < 65536 exactly
    f32x4 v = *(const f32x4*)(Wproj + (size_t)i * 4);
    u16x4 o;
    o[0] = f2bf(v[0]); o[1] = f2bf(v[1]); o[2] = f2bf(v[2]); o[3] = f2bf(v[3]);
    *(u16x4*)(wpb + (size_t)i * 4) = o;
  } else {
    const int n4 = MTOT * CDIM / 4;
    const int stride = ((int)gridDim.x - 3334) * 256;
    for (int i = (bid - 3334) * 256 + t; i < n4; i += stride) {
      f32x4 v = *(const f32x4*)(x + (size_t)i * 4);
      u16x4 o;
      o[0] = f2bf(v[0]); o[1] = f2bf(v[1]); o[2] = f2bf(v[2]); o[3] = f2bf(v[3]);
      *(u16x4*)(xb + (size_t)i * 4) = o;
    }
  }
}

// ---- 128(M)x256(N) tile, BK=32, 4 waves of 64x128, triple-buffered ----
// R12-proven (FROZEN): A bf16 via gl_lds, 72KB -> 2 blk/CU, counted vmcnt(6),
// 1 barrier/tile, 16B-slot swizzle slot^=(row>>1)&3, 0 bank conflicts.
template <int NT, bool SPLIT>
__global__ __launch_bounds__(256, 2) void k_gemmW(
    const unsigned short* __restrict__ A, const unsigned short* __restrict__ Bw,
    const float* __restrict__ bias,
    unsigned short* __restrict__ qo, unsigned short* __restrict__ ko,
    unsigned short* __restrict__ vo, float* __restrict__ fo) {
  // 72KB: A bufs 3x4096 ushorts at [0,12288); B bufs 3x8192 at [12288,36864).
  __shared__ __attribute__((aligned(16))) unsigned short smem[36864];
  const int t = threadIdx.x;  // 256
  const int l = t & 63;
  const int l15 = l & 15, lq = l >> 4;
  const int w = t >> 6;               // 4 waves
  const int wr = w >> 1, wc = w & 1;  // 2x2 grid, wave owns 64(M) x 128(N)
  const int bid = blockIdx.x;
  const int lb = (bid & 7) * ((int)gridDim.x >> 3) + (bid >> 3);
  const int mt = lb / NT, nt = lb % NT;
  const size_t m0 = (size_t)mt * 128;
  const int n0 = nt * 256;

  // A tile 128x32 = 8KB = 512 chunks (2/thread); B tile 256x32 = 16KB (4/thr).
  auto stage = [&](int kt, int bb) {
    unsigned short* dA = smem + bb * 4096;
#pragma unroll
    for (int q = 0; q < 2; ++q) {
      const int li = q * 256 + t;
      const int row = li >> 2, sl = li & 3;
      gl_lds16(A + (m0 + row) * CDIM + kt * 32 + ((sl ^ ((row >> 1) & 3)) << 3),
               &dA[li * 8]);
    }
    unsigned short* dB = smem + 12288 + bb * 8192;
#pragma unroll
    for (int q = 0; q < 4; ++q) {
      const int li = q * 256 + t;
      const int row = li >> 2, sl = li & 3;
      gl_lds16(Bw + (size_t)(n0 + row) * CDIM + kt * 32 +
                   ((sl ^ ((row >> 1) & 3)) << 3),
               &dB[li * 8]);
    }
  };

  f32x4 acc[4][8] = {};
  stage(0, 0);
  stage(1, 1);
  for (int kt = 0; kt < 16; ++kt) {
    const int cur = kt % 3;
    if (kt < 15) {
      asm volatile("s_waitcnt vmcnt(6)" ::: "memory");  // tile kt landed
    } else {
      asm volatile("s_waitcnt vmcnt(0)" ::: "memory");
    }
    __builtin_amdgcn_s_barrier();
    asm volatile("" ::: "memory");
    if (kt < 14) stage(kt + 2, (kt + 2) % 3);  // -> buffer freed at kt-1
    const unsigned short* bufA = smem + cur * 4096;
    const unsigned short* bufB = smem + 12288 + cur * 8192;
    bf16x8 af[4], bfv[8];
#pragma unroll
    for (int f = 0; f < 4; ++f) {
      const int r = wr * 64 + f * 16 + l15;
      af[f] = __builtin_bit_cast(
          bf16x8, *(const u32x4*)&bufA[r * 32 + ((lq ^ ((r >> 1) & 3)) << 3)]);
    }
#pragma unroll
    for (int c = 0; c < 8; ++c) {
      const int r = wc * 128 + c * 16 + l15;
      bfv[c] = __builtin_bit_cast(
          bf16x8, *(const u32x4*)&bufB[r * 32 + ((lq ^ ((r >> 1) & 3)) << 3)]);
    }
    __builtin_amdgcn_s_setprio(1);
#pragma unroll
    for (int f = 0; f < 4; ++f) {
#pragma unroll
      for (int c = 0; c < 8; ++c) acc[f][c] = mfma16(af[f], bfv[c], acc[f][c]);
    }
    __builtin_amdgcn_s_setprio(0);
    asm volatile("" ::: "memory");
  }

  // ---- LDS-staged coalesced epilogue (slot^row swizzled; 0 conflicts) ----
  __syncthreads();  // all waves done with tile buffers before repurposing
  if constexpr (SPLIT) {
    // wave region: 64 rows x 128 cols bf16 = 16KB (16 slots of 16B per row)
    unsigned short* ep = smem + w * 8192;
#pragma unroll
    for (int J = 0; J < 8; ++J) {
      const int colb = n0 + wc * 128 + J * 16 + l15;
      const float bv = bias[colb];
      const int sl0 = J * 2 + (l15 >> 3);
#pragma unroll
      for (int I = 0; I < 4; ++I) {
#pragma unroll
        for (int r = 0; r < 4; ++r) {
          const int row = I * 16 + lq * 4 + r;
          ep[row * 128 + ((sl0 ^ (row & 7)) << 3) + (l15 & 7)] =
              f2bf(acc[I][J][r] + bv);
        }
      }
    }
    asm volatile("s_waitcnt lgkmcnt(0)" ::: "memory");
    __builtin_amdgcn_s_barrier();
    // 256 sub-rows (64 m-rows x 4 head-chunks of 32 cols); 4 lanes/sub-row
#pragma unroll
    for (int rnd = 0; rnd < 16; ++rnd) {
      const int sub = rnd * 16 + (l >> 2);
      const int mloc = sub >> 2, hd = sub & 3;
      const int colh = n0 + wc * 128 + hd * 32;
      const int which = colh >> 9;
      const int hh = (colh >> 5) & 15;
      unsigned short* dst = which == 0 ? qo : (which == 1 ? ko : vo);
      const uint32_t mg = (uint32_t)(m0 + wr * 64 + mloc);
      const uint32_t bw_ = mg / 49u;
      const uint32_t nn = mg - bw_ * 49u;
      const int slot = hd * 4 + (l & 3);
      u32x4 v = *(const u32x4*)&ep[mloc * 128 + ((slot ^ (mloc & 7)) << 3)];
      *(u32x4*)&dst[((size_t)(bw_ * 16u + hh) * 49u + nn) * 32u + (l & 3) * 8] =
          v;
    }
  } else {
    // wave region: 64 rows x 64 cols f32 = 16KB; two column-halves
    float* ep32 = (float*)(smem) + w * 4096;
#pragma unroll
    for (int ch = 0; ch < 2; ++ch) {
#pragma unroll
      for (int J2 = 0; J2 < 4; ++J2) {
        const int colb = n0 + wc * 128 + ch * 64 + J2 * 16 + l15;
        const float bv = bias[colb];
        const int sl0 = J2 * 4 + (l15 >> 2);
#pragma unroll
        for (int I = 0; I < 4; ++I) {
#pragma unroll
          for (int r = 0; r < 4; ++r) {
            const int row = I * 16 + lq * 4 + r;
            ep32[row * 64 + ((sl0 ^ (row & 7)) << 2) + (l15 & 3)] =
                acc[I][ch * 4 + J2][r] + bv;
          }
        }
      }
      asm volatile("s_waitcnt lgkmcnt(0)" ::: "memory");
#pragma unroll
      for (int rnd = 0; rnd < 16; ++rnd) {
        const int row = rnd * 4 + (l >> 4);
        const int slot = l & 15;
        f32x4 v = *(const f32x4*)&ep32[row * 64 + ((slot ^ (row & 7)) << 2)];
        const size_t mg = m0 + wr * 64 + row;
        *(f32x4*)&fo[mg * CDIM + n0 + wc * 128 + ch * 64 + (l & 15) * 4] = v;
      }
      asm volatile("s_waitcnt lgkmcnt(0)" ::: "memory");
      asm volatile("" ::: "memory");
    }
  }
}

// ---- K2: window attention, one wave per (b,h); block-shared bf16 mask ----
// R12-proven structure. Scale folding: Q prescaled by ATT_SCALE*LOG2E in
// weff/bias, mask staged as m*LOG2E -> softmax uses exp2f directly (one
// v_exp_f32, which natively computes 2^x; deletes the scale & log2e muls).
__global__ __launch_bounds__(256) void k_attn(
    const unsigned short* __restrict__ qb, const unsigned short* __restrict__ kb,
    const unsigned short* __restrict__ vb, const float* __restrict__ mask,
    unsigned short* __restrict__ ao) {
  __shared__ __attribute__((aligned(16))) unsigned short sP[4][64 * 64];
  __shared__ __attribute__((aligned(16))) unsigned short sV[4][32 * 64];
  __shared__ __attribute__((aligned(16))) unsigned short sM[2432];
  const int t = threadIdx.x;
  const int l = t & 63, w = t >> 6;
  const int l15 = l & 15, lq = l >> 4;
  const int pair = blockIdx.x * 4 + w;
  const int h = pair & 15;
  const int bmask = (blockIdx.x >> 2) & 63;
  const int b = pair >> 4;
  const size_t base = (size_t)pair * (TOK * HDIM);
  unsigned short* P = sP[w];
  unsigned short* Vt = sV[w];

  // stage mask window once per block, prescaled by LOG2E
  {
    const float* msrc = mask + (size_t)bmask * (TOK * TOK);
    for (int idx = t; idx < TOK * TOK; idx += 256)
      sM[idx] = f2bf(msrc[idx] * LOG2E);
  }

  bf16x8 qf[4], kf[4];
#pragma unroll
  for (int i = 0; i < 4; i++)
    qf[i] = __builtin_bit_cast(
        bf16x8, *(const u32x4*)(qb + base + (size_t)(i * 16 + l15) * 32 + lq * 8));
#pragma unroll
  for (int i = 0; i < 4; i++)
    kf[i] = __builtin_bit_cast(
        bf16x8, *(const u32x4*)(kb + base + (size_t)(i * 16 + l15) * 32 + lq * 8));
  u32x4 vr[4];
#pragma unroll
  for (int j = 0; j < 4; j++)
    vr[j] = *(const u32x4*)(vb + base + (size_t)l * 32 + j * 8);

  f32x4 s[4][4];
  __builtin_amdgcn_s_setprio(1);
#pragma unroll
  for (int i = 0; i < 4; i++) {
#pragma unroll
    for (int j = 0; j < 4; j++) s[i][j] = mfma16(qf[i], kf[j], (f32x4)0.0f);
  }
  __builtin_amdgcn_s_setprio(0);

  const bool vok = (l < TOK);
  const int tsl = ((l >> 3) & 7);
  const int tlo = l & 7;
#pragma unroll
  for (int j = 0; j < 4; j++) {
#pragma unroll
    for (int c = 0; c < 4; c++) {
      uint32_t u = vr[j][c];
      int d0 = j * 8 + c * 2;
      Vt[(d0 + 0) * 64 + ((tsl ^ ((d0 + 0) & 7)) << 3) + tlo] =
          vok ? (unsigned short)(u & 0xFFFFu) : (unsigned short)0;
      Vt[(d0 + 1) * 64 + ((tsl ^ ((d0 + 1) & 7)) << 3) + tlo] =
          vok ? (unsigned short)(u >> 16) : (unsigned short)0;
    }
  }

  __syncthreads();  // sM visible to all waves

#pragma unroll
  for (int i = 0; i < 4; i++) {
#pragma unroll
    for (int r = 0; r < 4; r++) {
      int row = i * 16 + lq * 4 + r;
#pragma unroll
      for (int j = 0; j < 4; j++) {
        int col = j * 16 + l15;
        float xv = s[i][j][r];  // already scaled: Q prescaled by s*log2e
        if (col < TOK) {
          if (row < TOK) xv += bf2f(sM[row * TOK + col]);
        } else {
          xv = -1e30f;
        }
        s[i][j][r] = xv;
      }
    }
  }

  float rinv[4][4];
#pragma unroll
  for (int i = 0; i < 4; i++) {
#pragma unroll
    for (int r = 0; r < 4; r++) {
      float m = fmaxf(fmaxf(s[i][0][r], s[i][1][r]), fmaxf(s[i][2][r], s[i][3][r]));
      m = fmaxf(m, __shfl_xor(m, 1));
      m = fmaxf(m, __shfl_xor(m, 2));
      m = fmaxf(m, __shfl_xor(m, 4));
      m = fmaxf(m, __shfl_xor(m, 8));
      float sum = 0.f;
      int row = i * 16 + lq * 4 + r;
#pragma unroll
      for (int j = 0; j < 4; j++) {
        float p = exp2f(s[i][j][r] - m);
        sum += p;
        P[row * 64 + (((j * 2 + (l15 >> 3)) ^ (row & 7)) << 3) + (l15 & 7)] =
            f2bf(p);
      }
      sum += __shfl_xor(sum, 1);
      sum += __shfl_xor(sum, 2);
      sum += __shfl_xor(sum, 4);
      sum += __shfl_xor(sum, 8);
      rinv[i][r] = 1.0f / sum;
    }
  }

  asm volatile("s_waitcnt lgkmcnt(0)" ::: "memory");
  __builtin_amdgcn_sched_barrier(0);

  f32x4 o[4][2] = {};
#pragma unroll
  for (int ks = 0; ks < 2; ks++) {
    bf16x8 pa[4], vf[2];
#pragma unroll
    for (int i = 0; i < 4; i++)
      pa[i] = __builtin_bit_cast(
          bf16x8,
          *(const u32x4*)&P[(i * 16 + l15) * 64 + (((lq + ks * 4) ^ (l15 & 7)) << 3)]);
#pragma unroll
    for (int j = 0; j < 2; j++)
      vf[j] = __builtin_bit_cast(
          bf16x8,
          *(const u32x4*)&Vt[(j * 16 + l15) * 64 + (((lq + ks * 4) ^ (l15 & 7)) << 3)]);
    __builtin_amdgcn_s_setprio(1);
#pragma unroll
    for (int i = 0; i < 4; i++) {
#pragma unroll
      for (int j = 0; j < 2; j++) o[i][j] = mfma16(pa[i], vf[j], o[i][j]);
    }
    __builtin_amdgcn_s_setprio(0);
  }

#pragma unroll
  for (int i = 0; i < 4; i++) {
#pragma unroll
    for (int r = 0; r < 4; r++) {
      int row = i * 16 + lq * 4 + r;
      if (row < TOK) {
        float inv = rinv[i][r];
        size_t obase = ((size_t)b * TOK + row) * CDIM + h * HDIM;
#pragma unroll
        for (int j = 0; j < 2; j++)
          ao[obase + j * 16 + l15] = f2bf(o[i][j][r] * inv);
      }
    }
  }
}

extern "C" void kernel_launch(void* const* d_in, const int* in_sizes, int n_in,
                              void* d_out, int out_size, void* d_ws,
                              size_t ws_size, hipStream_t stream) {
  const float* x = (const float*)d_in[0];
  const float* mask = (const float*)d_in[1];
  const float* Wqkv = (const float*)d_in[2];
  const float* bqkv = (const float*)d_in[3];
  const float* Adown = (const float*)d_in[4];
  const float* Bup = (const float*)d_in[5];
  const float* Wproj = (const float*)d_in[6];
  const float* bproj = (const float*)d_in[7];
  float* out = (float*)d_out;
  char* ws = (char*)d_ws;

  size_t off = 0;
  auto alloc = [&](size_t bytes) {
    size_t o = off;
    off += (bytes + 255) & ~(size_t)255;
    return o;
  };
  const size_t qkv_elems = (size_t)NB * NHEAD * TOK * HDIM;
  unsigned short* weff = (unsigned short*)(ws + alloc((size_t)3 * CDIM * CDIM * 2));
  float* bq2 = (float*)(ws + alloc((size_t)3 * CDIM * 4));
  unsigned short* wpb = (unsigned short*)(ws + alloc((size_t)CDIM * CDIM * 2));
  unsigned short* qb = (unsigned short*)(ws + alloc(qkv_elems * 2 + 4096));
  unsigned short* kb = (unsigned short*)(ws + alloc(qkv_elems * 2 + 4096));
  unsigned short* vb = (unsigned short*)(ws + alloc(qkv_elems * 2 + 4096));
  unsigned short* xb = (unsigned short*)(ws + alloc((size_t)MTOT * CDIM * 2));
  unsigned short* ao = xb;  // xb dead after QKV GEMM; reuse for attention out

  // merged prep: weff(+Q prescale) | bq2 | wpb | xb  (one launch)
  k_prep_all<<<3334 + 2048, 256, 0, stream>>>(Wqkv, Bup, Adown, bqkv, Wproj, x,
                                              weff, bq2, wpb, xb);
  // QKV: 784 m-tiles x 6 n-tiles = 4704 blocks (4704 % 8 == 0)
  k_gemmW<6, true><<<(MTOT / 128) * 6, 256, 0, stream>>>(
      xb, weff, bq2, qb, kb, vb, nullptr);
  k_attn<<<NB * NHEAD / 4, 256, 0, stream>>>(qb, kb, vb, mask, ao);
  // proj: 784 m-tiles x 2 n-tiles = 1568 blocks (1568 % 8 == 0)
  k_gemmW<2, false><<<(MTOT / 128) * 2, 256, 0, stream>>>(
      ao, wpb, bproj, nullptr, nullptr, nullptr, out);
}

// Round 18
// 512.478 us; speedup vs baseline: 1.0183x; 1.0183x over previous
//
#include <hip/hip_runtime.h>
#include <stdint.h>

typedef __attribute__((ext_vector_type(4))) float f32x4;
typedef __attribute__((ext_vector_type(8))) __bf16 bf16x8;
typedef __attribute__((ext_vector_type(4))) unsigned int u32x4;
typedef __attribute__((ext_vector_type(4))) unsigned short u16x4;

#define TOK 49
#define NHEAD 16
#define HDIM 32
#define CDIM 512
#define NB 2048
#define MTOT (NB * TOK) /* 100352 */
#define ATT_SCALE 0.17677669529663687f

__device__ __forceinline__ unsigned short f2bf(float f) {
  return __builtin_bit_cast(unsigned short, (__bf16)f);
}
__device__ __forceinline__ float bf2f(unsigned short u) {
  return __builtin_bit_cast(float, (uint32_t)u << 16);
}

__device__ __forceinline__ void gl_lds16(const void* g, const void* lds) {
  __builtin_amdgcn_global_load_lds(
      (__attribute__((address_space(1))) void*)(uintptr_t)g,
      (__attribute__((address_space(3))) void*)(uint32_t)(uintptr_t)lds,
      16, 0, 0);
}

__device__ __forceinline__ f32x4 mfma16(bf16x8 a, bf16x8 b, f32x4 c) {
  return __builtin_amdgcn_mfma_f32_16x16x32_bf16(a, b, c, 0, 0, 0);
}

// ---- K0a: W_eff = W_qkv + B_up @ A_down, to bf16 [1536][512] ----
__global__ __launch_bounds__(256) void k_prep_weff(
    const float* __restrict__ Wqkv, const float* __restrict__ Bup,
    const float* __restrict__ Adown, unsigned short* __restrict__ weff) {
  int idx = blockIdx.x * 256 + threadIdx.x;
  if (idx >= 3 * CDIM * CDIM) return;
  int o = idx >> 9, i = idx & 511;
  float v = Wqkv[idx];
#pragma unroll
  for (int r = 0; r < 4; r++) v += Bup[o * 4 + r] * Adown[r * 512 + i];
  weff[idx] = f2bf(v);
}

// ---- K0b: fp32 -> bf16 vectorized convert ----
__global__ __launch_bounds__(256) void k_conv4(
    const float* __restrict__ src, unsigned short* __restrict__ dst, int n4) {
  for (int i = blockIdx.x * blockDim.x + threadIdx.x; i < n4;
       i += gridDim.x * blockDim.x) {
    f32x4 v = *(const f32x4*)(src + (size_t)i * 4);
    u16x4 o;
    o[0] = f2bf(v[0]); o[1] = f2bf(v[1]); o[2] = f2bf(v[2]); o[3] = f2bf(v[3]);
    *(u16x4*)(dst + (size_t)i * 4) = o;
  }
}

// ---- 128(M)x256(N) tile, BK=32, 4 waves of 64x128, triple-buffered ----
// R12-proven (FROZEN): A bf16 via gl_lds, 72KB -> 2 blk/CU, counted vmcnt(6),
// 1 barrier/tile, 16B-slot swizzle slot^=(row>>1)&3, 0 bank conflicts.
template <int NT, bool SPLIT>
__global__ __launch_bounds__(256, 2) void k_gemmW(
    const unsigned short* __restrict__ A, const unsigned short* __restrict__ Bw,
    const float* __restrict__ bias,
    unsigned short* __restrict__ qo, unsigned short* __restrict__ ko,
    unsigned short* __restrict__ vo, float* __restrict__ fo) {
  // 72KB: A bufs 3x4096 ushorts at [0,12288); B bufs 3x8192 at [12288,36864).
  __shared__ __attribute__((aligned(16))) unsigned short smem[36864];
  const int t = threadIdx.x;  // 256
  const int l = t & 63;
  const int l15 = l & 15, lq = l >> 4;
  const int w = t >> 6;               // 4 waves
  const int wr = w >> 1, wc = w & 1;  // 2x2 grid, wave owns 64(M) x 128(N)
  const int bid = blockIdx.x;
  const int lb = (bid & 7) * ((int)gridDim.x >> 3) + (bid >> 3);
  const int mt = lb / NT, nt = lb % NT;
  const size_t m0 = (size_t)mt * 128;
  const int n0 = nt * 256;

  // A tile 128x32 = 8KB = 512 chunks (2/thread); B tile 256x32 = 16KB (4/thr).
  auto stage = [&](int kt, int bb) {
    unsigned short* dA = smem + bb * 4096;
#pragma unroll
    for (int q = 0; q < 2; ++q) {
      const int li = q * 256 + t;
      const int row = li >> 2, sl = li & 3;
      gl_lds16(A + (m0 + row) * CDIM + kt * 32 + ((sl ^ ((row >> 1) & 3)) << 3),
               &dA[li * 8]);
    }
    unsigned short* dB = smem + 12288 + bb * 8192;
#pragma unroll
    for (int q = 0; q < 4; ++q) {
      const int li = q * 256 + t;
      const int row = li >> 2, sl = li & 3;
      gl_lds16(Bw + (size_t)(n0 + row) * CDIM + kt * 32 +
                   ((sl ^ ((row >> 1) & 3)) << 3),
               &dB[li * 8]);
    }
  };

  f32x4 acc[4][8] = {};
  stage(0, 0);
  stage(1, 1);
  for (int kt = 0; kt < 16; ++kt) {
    const int cur = kt % 3;
    if (kt < 15) {
      asm volatile("s_waitcnt vmcnt(6)" ::: "memory");  // tile kt landed
    } else {
      asm volatile("s_waitcnt vmcnt(0)" ::: "memory");
    }
    __builtin_amdgcn_s_barrier();
    asm volatile("" ::: "memory");
    if (kt < 14) stage(kt + 2, (kt + 2) % 3);  // -> buffer freed at kt-1
    const unsigned short* bufA = smem + cur * 4096;
    const unsigned short* bufB = smem + 12288 + cur * 8192;
    bf16x8 af[4], bfv[8];
#pragma unroll
    for (int f = 0; f < 4; ++f) {
      const int r = wr * 64 + f * 16 + l15;
      af[f] = __builtin_bit_cast(
          bf16x8, *(const u32x4*)&bufA[r * 32 + ((lq ^ ((r >> 1) & 3)) << 3)]);
    }
#pragma unroll
    for (int c = 0; c < 8; ++c) {
      const int r = wc * 128 + c * 16 + l15;
      bfv[c] = __builtin_bit_cast(
          bf16x8, *(const u32x4*)&bufB[r * 32 + ((lq ^ ((r >> 1) & 3)) << 3)]);
    }
    __builtin_amdgcn_s_setprio(1);
#pragma unroll
    for (int f = 0; f < 4; ++f) {
#pragma unroll
      for (int c = 0; c < 8; ++c) acc[f][c] = mfma16(af[f], bfv[c], acc[f][c]);
    }
    __builtin_amdgcn_s_setprio(0);
    asm volatile("" ::: "memory");
  }

  // ---- LDS-staged coalesced epilogue (slot^row swizzled; 0 conflicts) ----
  __syncthreads();  // all waves done with tile buffers before repurposing
  if constexpr (SPLIT) {
    // wave region: 64 rows x 128 cols bf16 = 16KB (16 slots of 16B per row)
    unsigned short* ep = smem + w * 8192;
#pragma unroll
    for (int J = 0; J < 8; ++J) {
      const int colb = n0 + wc * 128 + J * 16 + l15;
      const float bv = bias[colb];
      const int sl0 = J * 2 + (l15 >> 3);
#pragma unroll
      for (int I = 0; I < 4; ++I) {
#pragma unroll
        for (int r = 0; r < 4; ++r) {
          const int row = I * 16 + lq * 4 + r;
          ep[row * 128 + ((sl0 ^ (row & 7)) << 3) + (l15 & 7)] =
              f2bf(acc[I][J][r] + bv);
        }
      }
    }
    asm volatile("s_waitcnt lgkmcnt(0)" ::: "memory");
    __builtin_amdgcn_s_barrier();
    // 256 sub-rows (64 m-rows x 4 head-chunks of 32 cols); 4 lanes/sub-row
#pragma unroll
    for (int rnd = 0; rnd < 16; ++rnd) {
      const int sub = rnd * 16 + (l >> 2);
      const int mloc = sub >> 2, hd = sub & 3;
      const int colh = n0 + wc * 128 + hd * 32;
      const int which = colh >> 9;
      const int hh = (colh >> 5) & 15;
      unsigned short* dst = which == 0 ? qo : (which == 1 ? ko : vo);
      const uint32_t mg = (uint32_t)(m0 + wr * 64 + mloc);
      const uint32_t bw_ = mg / 49u;
      const uint32_t nn = mg - bw_ * 49u;
      const int slot = hd * 4 + (l & 3);
      u32x4 v = *(const u32x4*)&ep[mloc * 128 + ((slot ^ (mloc & 7)) << 3)];
      *(u32x4*)&dst[((size_t)(bw_ * 16u + hh) * 49u + nn) * 32u + (l & 3) * 8] =
          v;
    }
  } else {
    // wave region: 64 rows x 64 cols f32 = 16KB; two column-halves
    float* ep32 = (float*)(smem) + w * 4096;
#pragma unroll
    for (int ch = 0; ch < 2; ++ch) {
#pragma unroll
      for (int J2 = 0; J2 < 4; ++J2) {
        const int colb = n0 + wc * 128 + ch * 64 + J2 * 16 + l15;
        const float bv = bias[colb];
        const int sl0 = J2 * 4 + (l15 >> 2);
#pragma unroll
        for (int I = 0; I < 4; ++I) {
#pragma unroll
          for (int r = 0; r < 4; ++r) {
            const int row = I * 16 + lq * 4 + r;
            ep32[row * 64 + ((sl0 ^ (row & 7)) << 2) + (l15 & 3)] =
                acc[I][ch * 4 + J2][r] + bv;
          }
        }
      }
      asm volatile("s_waitcnt lgkmcnt(0)" ::: "memory");
#pragma unroll
      for (int rnd = 0; rnd < 16; ++rnd) {
        const int row = rnd * 4 + (l >> 4);
        const int slot = l & 15;
        f32x4 v = *(const f32x4*)&ep32[row * 64 + ((slot ^ (row & 7)) << 2)];
        const size_t mg = m0 + wr * 64 + row;
        *(f32x4*)&fo[mg * CDIM + n0 + wc * 128 + ch * 64 + (l & 15) * 4] = v;
      }
      asm volatile("s_waitcnt lgkmcnt(0)" ::: "memory");
      asm volatile("" ::: "memory");
    }
  }
}

// ---- K2: window attention, one wave per (b,h); block-shared bf16 mask ----
// R12/R15-proven best (FROZEN).
__global__ __launch_bounds__(256) void k_attn(
    const unsigned short* __restrict__ qb, const unsigned short* __restrict__ kb,
    const unsigned short* __restrict__ vb, const float* __restrict__ mask,
    unsigned short* __restrict__ ao) {
  __shared__ __attribute__((aligned(16))) unsigned short sP[4][64 * 64];
  __shared__ __attribute__((aligned(16))) unsigned short sV[4][32 * 64];
  __shared__ __attribute__((aligned(16))) unsigned short sM[2432];
  const int t = threadIdx.x;
  const int l = t & 63, w = t >> 6;
  const int l15 = l & 15, lq = l >> 4;
  const int pair = blockIdx.x * 4 + w;
  const int h = pair & 15;
  const int bmask = (blockIdx.x >> 2) & 63;
  const int b = pair >> 4;
  const size_t base = (size_t)pair * (TOK * HDIM);
  unsigned short* P = sP[w];
  unsigned short* Vt = sV[w];

  // stage mask window once per block (coalesced f32 reads, bf16 store)
  {
    const float* msrc = mask + (size_t)bmask * (TOK * TOK);
    for (int idx = t; idx < TOK * TOK; idx += 256) sM[idx] = f2bf(msrc[idx]);
  }

  bf16x8 qf[4], kf[4];
#pragma unroll
  for (int i = 0; i < 4; i++)
    qf[i] = __builtin_bit_cast(
        bf16x8, *(const u32x4*)(qb + base + (size_t)(i * 16 + l15) * 32 + lq * 8));
#pragma unroll
  for (int i = 0; i < 4; i++)
    kf[i] = __builtin_bit_cast(
        bf16x8, *(const u32x4*)(kb + base + (size_t)(i * 16 + l15) * 32 + lq * 8));
  u32x4 vr[4];
#pragma unroll
  for (int j = 0; j < 4; j++)
    vr[j] = *(const u32x4*)(vb + base + (size_t)l * 32 + j * 8);

  f32x4 s[4][4];
  __builtin_amdgcn_s_setprio(1);
#pragma unroll
  for (int i = 0; i < 4; i++) {
#pragma unroll
    for (int j = 0; j < 4; j++) s[i][j] = mfma16(qf[i], kf[j], (f32x4)0.0f);
  }
  __builtin_amdgcn_s_setprio(0);

  const bool vok = (l < TOK);
  const int tsl = ((l >> 3) & 7);
  const int tlo = l & 7;
#pragma unroll
  for (int j = 0; j < 4; j++) {
#pragma unroll
    for (int c = 0; c < 4; c++) {
      uint32_t u = vr[j][c];
      int d0 = j * 8 + c * 2;
      Vt[(d0 + 0) * 64 + ((tsl ^ ((d0 + 0) & 7)) << 3) + tlo] =
          vok ? (unsigned short)(u & 0xFFFFu) : (unsigned short)0;
      Vt[(d0 + 1) * 64 + ((tsl ^ ((d0 + 1) & 7)) << 3) + tlo] =
          vok ? (unsigned short)(u >> 16) : (unsigned short)0;
    }
  }

  __syncthreads();  // sM visible to all waves

#pragma unroll
  for (int i = 0; i < 4; i++) {
#pragma unroll
    for (int r = 0; r < 4; r++) {
      int row = i * 16 + lq * 4 + r;
#pragma unroll
      for (int j = 0; j < 4; j++) {
        int col = j * 16 + l15;
        float xv = s[i][j][r] * ATT_SCALE;
        if (col < TOK) {
          if (row < TOK) xv += bf2f(sM[row * TOK + col]);
        } else {
          xv = -1e30f;
        }
        s[i][j][r] = xv;
      }
    }
  }

  float rinv[4][4];
#pragma unroll
  for (int i = 0; i < 4; i++) {
#pragma unroll
    for (int r = 0; r < 4; r++) {
      float m = fmaxf(fmaxf(s[i][0][r], s[i][1][r]), fmaxf(s[i][2][r], s[i][3][r]));
      m = fmaxf(m, __shfl_xor(m, 1));
      m = fmaxf(m, __shfl_xor(m, 2));
      m = fmaxf(m, __shfl_xor(m, 4));
      m = fmaxf(m, __shfl_xor(m, 8));
      float sum = 0.f;
      int row = i * 16 + lq * 4 + r;
#pragma unroll
      for (int j = 0; j < 4; j++) {
        float p = __expf(s[i][j][r] - m);
        sum += p;
        P[row * 64 + (((j * 2 + (l15 >> 3)) ^ (row & 7)) << 3) + (l15 & 7)] =
            f2bf(p);
      }
      sum += __shfl_xor(sum, 1);
      sum += __shfl_xor(sum, 2);
      sum += __shfl_xor(sum, 4);
      sum += __shfl_xor(sum, 8);
      rinv[i][r] = 1.0f / sum;
    }
  }

  asm volatile("s_waitcnt lgkmcnt(0)" ::: "memory");
  __builtin_amdgcn_sched_barrier(0);

  f32x4 o[4][2] = {};
#pragma unroll
  for (int ks = 0; ks < 2; ks++) {
    bf16x8 pa[4], vf[2];
#pragma unroll
    for (int i = 0; i < 4; i++)
      pa[i] = __builtin_bit_cast(
          bf16x8,
          *(const u32x4*)&P[(i * 16 + l15) * 64 + (((lq + ks * 4) ^ (l15 & 7)) << 3)]);
#pragma unroll
    for (int j = 0; j < 2; j++)
      vf[j] = __builtin_bit_cast(
          bf16x8,
          *(const u32x4*)&Vt[(j * 16 + l15) * 64 + (((lq + ks * 4) ^ (l15 & 7)) << 3)]);
    __builtin_amdgcn_s_setprio(1);
#pragma unroll
    for (int i = 0; i < 4; i++) {
#pragma unroll
      for (int j = 0; j < 2; j++) o[i][j] = mfma16(pa[i], vf[j], o[i][j]);
    }
    __builtin_amdgcn_s_setprio(0);
  }

#pragma unroll
  for (int i = 0; i < 4; i++) {
#pragma unroll
    for (int r = 0; r < 4; r++) {
      int row = i * 16 + lq * 4 + r;
      if (row < TOK) {
        float inv = rinv[i][r];
        size_t obase = ((size_t)b * TOK + row) * CDIM + h * HDIM;
#pragma unroll
        for (int j = 0; j < 2; j++)
          ao[obase + j * 16 + l15] = f2bf(o[i][j][r] * inv);
      }
    }
  }
}

extern "C" void kernel_launch(void* const* d_in, const int* in_sizes, int n_in,
                              void* d_out, int out_size, void* d_ws,
                              size_t ws_size, hipStream_t stream) {
  const float* x = (const float*)d_in[0];
  const float* mask = (const float*)d_in[1];
  const float* Wqkv = (const float*)d_in[2];
  const float* bqkv = (const float*)d_in[3];
  const float* Adown = (const float*)d_in[4];
  const float* Bup = (const float*)d_in[5];
  const float* Wproj = (const float*)d_in[6];
  const float* bproj = (const float*)d_in[7];
  float* out = (float*)d_out;
  char* ws = (char*)d_ws;

  size_t off = 0;
  auto alloc = [&](size_t bytes) {
    size_t o = off;
    off += (bytes + 255) & ~(size_t)255;
    return o;
  };
  const size_t qkv_elems = (size_t)NB * NHEAD * TOK * HDIM;
  unsigned short* weff = (unsigned short*)(ws + alloc((size_t)3 * CDIM * CDIM * 2));
  unsigned short* wpb = (unsigned short*)(ws + alloc((size_t)CDIM * CDIM * 2));
  unsigned short* qb = (unsigned short*)(ws + alloc(qkv_elems * 2 + 4096));
  unsigned short* kb = (unsigned short*)(ws + alloc(qkv_elems * 2 + 4096));
  unsigned short* vb = (unsigned short*)(ws + alloc(qkv_elems * 2 + 4096));
  unsigned short* xb = (unsigned short*)(ws + alloc((size_t)MTOT * CDIM * 2));
  unsigned short* ao = xb;  // xb dead after QKV GEMM; reuse for attention out

  k_prep_weff<<<(3 * CDIM * CDIM + 255) / 256, 256, 0, stream>>>(Wqkv, Bup,
                                                                 Adown, weff);
  k_conv4<<<256, 256, 0, stream>>>(Wproj, wpb, CDIM * CDIM / 4);
  k_conv4<<<2048, 256, 0, stream>>>(x, xb, MTOT * CDIM / 4);
  // QKV: 784 m-tiles x 6 n-tiles = 4704 blocks (4704 % 8 == 0)
  k_gemmW<6, true><<<(MTOT / 128) * 6, 256, 0, stream>>>(
      xb, weff, bqkv, qb, kb, vb, nullptr);
  k_attn<<<NB * NHEAD / 4, 256, 0, stream>>>(qb, kb, vb, mask, ao);
  // proj: 784 m-tiles x 2 n-tiles = 1568 blocks (1568 % 8 == 0)
  k_gemmW<2, false><<<(MTOT / 128) * 2, 256, 0, stream>>>(
      ao, wpb, bproj, nullptr, nullptr, nullptr, out);
}